// Round 11
// baseline (156.244 us; speedup 1.0000x reference)
//
#include <hip/hip_runtime.h>
#include <hip/hip_bf16.h>

// GATConv, N=8192, F_in=F_out=128, dense 0/1 adjacency (int32).
// Rank-1 logits: e_ij = LeakyReLU(es_i + ed_j), es = X@(W@a_src), ed = X@(W@a_dst).
// exp safe in f32 -> additive softmax partials, no max-shift.
//
// R11: barrier-free k2. k1 emits H in MFMA-B-fragment-major layout
// VB[jb][cb][lane][8] (wave frag load = contiguous 1 KB, L2-resident), so k2
// has NO LDS / NO barriers in the main loop: per-wave free-running pipeline
// with 2-iter-deep A/ed register prefetch. Epilogue: LDS merge of the 4
// j-slice waves + plain stores (no global atomics -> replay-safe, no zeroing).

typedef __bf16 bf16_t;
typedef bf16_t bf16x8 __attribute__((ext_vector_type(8)));
typedef float  f32x4  __attribute__((ext_vector_type(4)));
typedef int    i32x4  __attribute__((ext_vector_type(4)));

#define NN 8192
#define DD 128
#define JSPLIT 4

// ---- K1: fused wv = W@a_{src,dst}; es/ed; VB = frag-major bf16(X@W) ----
__global__ __launch_bounds__(512) void k1_fused(const float* __restrict__ X,
                                                const float* __restrict__ W,
                                                const float* __restrict__ a_src,
                                                const float* __restrict__ a_dst,
                                                float* __restrict__ es,
                                                float* __restrict__ edv,
                                                bf16_t* __restrict__ VB) {
  __shared__ float Wl[DD * DD];    // 64 KB; [0..256) wsv/wdv, [256..320) es/ed scratch
  __shared__ bf16_t Tl[DD][40];    // transposed H tile [col][row]
  const int t = threadIdx.x;
  const int rb = blockIdx.x << 5;  // 32 H-rows per block

  if (t < 256) {
    const int k = t & 127;
    const float* av = (t < 128) ? a_src : a_dst;
    const f32x4* wrow = (const f32x4*)(W + k * DD);
    float s = 0.f;
    #pragma unroll
    for (int c4 = 0; c4 < 32; ++c4) {
      const f32x4 wv = wrow[c4];
      const f32x4 avv = *(const f32x4*)(av + c4 * 4);
      s += wv[0] * avv[0] + wv[1] * avv[1] + wv[2] * avv[2] + wv[3] * avv[3];
    }
    Wl[t] = s;
  }
  if (t < 64) Wl[256 + t] = 0.f;
  __syncthreads();

  {
    const int r = t >> 4, part = t & 15;
    const f32x4* xrow = (const f32x4*)(X + (size_t)(rb + r) * DD + part * 8);
    float s = 0.f, d = 0.f;
    #pragma unroll
    for (int q = 0; q < 2; ++q) {
      const f32x4 xv = xrow[q];
      const f32x4 sv = *(const f32x4*)(Wl + part * 8 + q * 4);
      const f32x4 dv = *(const f32x4*)(Wl + 128 + part * 8 + q * 4);
      s += xv[0] * sv[0] + xv[1] * sv[1] + xv[2] * sv[2] + xv[3] * sv[3];
      d += xv[0] * dv[0] + xv[1] * dv[1] + xv[2] * dv[2] + xv[3] * dv[3];
    }
    atomicAdd(&Wl[256 + r], s);
    atomicAdd(&Wl[288 + r], d);
  }
  __syncthreads();
  if (t < 32) {
    es[rb + t] = Wl[256 + t];
  } else if (t < 64) {
    edv[rb + t - 32] = Wl[288 + t - 32];
  }
  __syncthreads();

  for (int idx = t; idx < DD * DD; idx += 512) Wl[idx] = W[idx];
  __syncthreads();

  const int c = t & 127;
  const int r0 = t >> 7;
  for (int rr = 0; rr < 8; ++rr) {
    const int r = (rr << 2) + r0;
    const f32x4* xrow = (const f32x4*)(X + (size_t)(rb + r) * DD);
    float acc = 0.f;
    #pragma unroll
    for (int k4 = 0; k4 < 32; ++k4) {
      const f32x4 xv = xrow[k4];
      acc += xv[0] * Wl[(k4 * 4 + 0) * DD + c] + xv[1] * Wl[(k4 * 4 + 1) * DD + c] +
             xv[2] * Wl[(k4 * 4 + 2) * DD + c] + xv[3] * Wl[(k4 * 4 + 3) * DD + c];
    }
    Tl[c][r] = (bf16_t)acc;
  }
  __syncthreads();

  // write-out in B-fragment-major layout:
  // VB[((jb*8 + cb)*64 + lane)*8 + e] = H[jb*32 + (lane>>4)*8 + e][cb*16 + (lane&15)]
  // this block: jb = rb>>5 (its 32 rows), 2 jb-halves? no: one jb per block.
  {
    const int cb = t >> 6;          // 0..7 (one col-block per wave)
    const int lane = t & 63;
    const int col = (cb << 4) + (lane & 15);
    const int rloc = (lane >> 4) << 3;
    const bf16x8 u = *(const bf16x8*)&Tl[col][rloc];
    *(bf16x8*)(VB + ((((size_t)(rb >> 5) << 3) + cb) * 64 + lane) * 8) = u;
  }
}

// ---- K2: barrier-free masked GEMM. 2048 blocks x 256 thr (4 waves). ----
// Block = 16 rows x j-quarter (2048). Wave ws owns j-slice [jq0+ws*512, +512),
// 16 iters of 32 j. Lane (l16,lk): row rb+l16, j = slice + it*32 + lk*8 +0..7.
// Per iter: 8 VB frag loads (L2, coalesced) + P in-reg (8 exp) + A/ed(it+2)
// register prefetch + 8 MFMA. No LDS, no barriers until the epilogue merge.
__global__ __launch_bounds__(256, 3) void k2_gat(const int* __restrict__ A,
                                                 const float* __restrict__ es,
                                                 const float* __restrict__ edv,
                                                 const bf16_t* __restrict__ VB,
                                                 float* __restrict__ num,
                                                 float* __restrict__ denP) {
  __shared__ float ML[16 * DD];  // 8 KB merge
  __shared__ float denL[16];
  const int t = threadIdx.x;
  const int lane = t & 63, ws = t >> 6;
  const int l16 = lane & 15, lk = lane >> 4;
  const int rb = (blockIdx.x >> 2) << 4;  // 16 rows
  const int jq = blockIdx.x & 3;
  const int jq0 = jq << 11;
  const int jbase = jq0 + (ws << 9);      // wave's 512-j slice

  const int r0 = rb + l16;
  const float es0 = es[r0];

  const int* pA = A + (size_t)r0 * NN + jbase + (lk << 3);
  const float* ped = edv + jbase + (lk << 3);
  const bf16_t* pV = VB + (((size_t)(jbase >> 5) << 3) * 64 + lane) * 8;
  const int jth0 = jbase + (lk << 3);  // j of element e=0 at iter 0

  f32x4 acc[8];
  #pragma unroll
  for (int cb = 0; cb < 8; ++cb) acc[cb] = f32x4{0.f, 0.f, 0.f, 0.f};
  float dsum = 0.f;

  // 2-phase register staging of A/ed (2 iters deep)
  i32x4 aA0 = *(const i32x4*)pA, aB0 = *(const i32x4*)(pA + 4);
  f32x4 eA0 = *(const f32x4*)ped, eB0 = *(const f32x4*)(ped + 4);
  i32x4 aA1 = *(const i32x4*)(pA + 32), aB1 = *(const i32x4*)(pA + 36);
  f32x4 eA1 = *(const f32x4*)(ped + 32), eB1 = *(const f32x4*)(ped + 36);

  auto step = [&](int it, i32x4& aA, i32x4& aB, f32x4& eA, f32x4& eB) {
    // (1) VB fragment loads for this iter (8 x 16B, wave-contiguous 1KB each)
    const bf16_t* pvi = pV + (size_t)it * 4096;
    bf16x8 vb[8];
    #pragma unroll
    for (int cb = 0; cb < 8; ++cb) vb[cb] = *(const bf16x8*)(pvi + (cb << 9));
    // (2) P in-reg from the 2-iter-old A/ed registers
    const int jit = jth0 + (it << 5);
    bf16x8 pa;
    float s = 0.f;
    #pragma unroll
    for (int e = 0; e < 8; ++e) {
      const int av = (e < 4) ? aA[e] : aB[e - 4];
      const float edq = (e < 4) ? eA[e] : eB[e - 4];
      float x = es0 + edq;
      x = fmaxf(x, 0.2f * x);
      const float p = (av > 0 || (jit + e) == r0) ? __expf(x) : 0.f;
      s += p;
      pa[e] = (bf16_t)p;
    }
    dsum += s;
    // (3) prefetch iter it+2 into the just-freed phase registers
    if (it + 2 < 16) {
      const int off = (it + 2) << 5;
      aA = *(const i32x4*)(pA + off);
      aB = *(const i32x4*)(pA + off + 4);
      eA = *(const f32x4*)(ped + off);
      eB = *(const f32x4*)(ped + off + 4);
    }
    // (4) MFMA
    #pragma unroll
    for (int cb = 0; cb < 8; ++cb)
      acc[cb] = __builtin_amdgcn_mfma_f32_16x16x32_bf16(pa, vb[cb], acc[cb], 0, 0, 0);
  };

  #pragma unroll 1
  for (int it2 = 0; it2 < 8; ++it2) {
    step(2 * it2, aA0, aB0, eA0, eB0);
    step(2 * it2 + 1, aA1, aB1, eA1, eB1);
  }

  // ---- epilogue: merge 4 waves via LDS, plain stores ----
  // dsum: reduce over lk (lanes l16, l16+16, +32, +48 share row r0)
  dsum += __shfl_xor(dsum, 16, 64);
  dsum += __shfl_xor(dsum, 32, 64);
  if (t < 16) denL[t] = 0.f;
  for (int i = t; i < 16 * DD; i += 256) ML[i] = 0.f;
  __syncthreads();
  if (lane < 16) atomicAdd(&denL[lane], dsum);
  #pragma unroll
  for (int cb = 0; cb < 8; ++cb) {
    #pragma unroll
    for (int rg = 0; rg < 4; ++rg) {
      // C/D: row = lk*4 + rg, col = cb*16 + l16 (validated layout)
      atomicAdd(&ML[((lk << 2) + rg) * DD + (cb << 4) + l16], acc[cb][rg]);
    }
  }
  __syncthreads();
  {
    const int row = t >> 4;
    const int c0 = (t & 15) << 3;
    float* nq = num + (size_t)jq * (NN * DD) + (size_t)(rb + row) * DD + c0;
    *(f32x4*)nq = *(const f32x4*)&ML[row * DD + c0];
    *(f32x4*)(nq + 4) = *(const f32x4*)&ML[row * DD + c0 + 4];
  }
  if (t < 16) denP[(size_t)jq * NN + rb + t] = denL[t];
}

// ---- K3: out = elu( (sum_q num_q) / (sum_q den_q) ) ----
__global__ __launch_bounds__(256) void k3_fin(const float* __restrict__ num,
                                              const float* __restrict__ denP,
                                              float* __restrict__ out) {
  const int g = blockIdx.x * 256 + threadIdx.x;
  const size_t b = (size_t)g * 8;
  const int row = (int)(b >> 7);
  float den = 0.f;
  #pragma unroll
  for (int q = 0; q < JSPLIT; ++q) den += denP[(size_t)q * NN + row];
  const float rd = 1.f / den;
  f32x4 s0 = {0.f, 0.f, 0.f, 0.f}, s1 = {0.f, 0.f, 0.f, 0.f};
  #pragma unroll
  for (int q = 0; q < JSPLIT; ++q) {
    const float* nb = num + (size_t)q * (NN * DD);
    s0 += *(const f32x4*)(nb + b);
    s1 += *(const f32x4*)(nb + b + 4);
  }
  #pragma unroll
  for (int e = 0; e < 4; ++e) {
    float v = s0[e] * rd;
    s0[e] = v > 0.f ? v : (__expf(v) - 1.f);
    v = s1[e] * rd;
    s1[e] = v > 0.f ? v : (__expf(v) - 1.f);
  }
  *(f32x4*)(out + b) = s0;
  *(f32x4*)(out + b + 4) = s1;
}

extern "C" void kernel_launch(void* const* d_in, const int* in_sizes, int n_in,
                              void* d_out, int out_size, void* d_ws, size_t ws_size,
                              hipStream_t stream) {
  const float* X = (const float*)d_in[0];
  const int* A = (const int*)d_in[1];
  const float* W = (const float*)d_in[2];
  const float* a_src = (const float*)d_in[3];
  const float* a_dst = (const float*)d_in[4];
  float* out = (float*)d_out;

  char* w = (char*)d_ws;
  bf16_t* VB = (bf16_t*)(w + 0);        // 2 MB frag-major H
  float* es = (float*)(w + 2097152);    // 32 KB
  float* edv = (float*)(w + 2129920);   // 32 KB
  float* denP = (float*)(w + 2162688);  // 4 x 32 KB
  float* num = (float*)(w + 2293760);   // 4 x 4 MB (total ~18.5 MB)

  hipLaunchKernelGGL(k1_fused, dim3(256), dim3(512), 0, stream, X, W, a_src, a_dst, es,
                     edv, VB);
  hipLaunchKernelGGL(k2_gat, dim3(2048), dim3(256), 0, stream, A, es, edv, VB, num,
                     denP);
  hipLaunchKernelGGL(k3_fin, dim3(512), dim3(256), 0, stream, num, denP, out);
}